// Round 1
// baseline (520.044 us; speedup 1.0000x reference)
//
#include <hip/hip_runtime.h>

#define D   780   // binom(40,2)
#define NG  39    // gates
#define NP  38    // rotation pairs per gate
#define KT  16    // column tile for row-phase
#define PAD 17    // LDS row pad (floats) to break bank conflicts

// index of basis state {p,q}, p<q, in lexicographic combinations(range(40),2)
__device__ __forceinline__ int pair_idx(int p, int q) {
  return (p * (79 - p)) / 2 + (q - p - 1);
}

// Phase A: S = rho @ V^T. Each wave owns one contiguous 780-float row.
// Column rotation within a row: v[i] <- c*v[i] - s*v[j]; v[j] <- s*v[i] + c*v[j]
// where i = idx({g,c}), j = idx({g+1,c}).
__global__ __launch_bounds__(256) void rbs_col_kernel(
    const float* __restrict__ rho, const float* __restrict__ ang,
    float* __restrict__ out) {
  __shared__ float csc[NG], css[NG];
  __shared__ float vbuf[4][D];            // one 780-float row per wave
  const int tid = threadIdx.x;
  if (tid < NG) {
    float s, c;
    sincosf(ang[tid], &s, &c);
    csc[tid] = c; css[tid] = s;
  }
  __syncthreads();

  const int wave = tid >> 6, lane = tid & 63;
  const size_t row = (size_t)blockIdx.x * 4 + wave;   // global row id (b*780 + r)
  const float4* src = (const float4*)(rho + row * (size_t)D);
  float* v = vbuf[wave];
  float4* v4 = (float4*)v;                            // 3120B row stride: 16B aligned

  for (int e = lane; e < D / 4; e += 64) v4[e] = src[e];   // 195 float4 per row
  __builtin_amdgcn_wave_barrier();

  for (int g = 0; g < NG; ++g) {
    if (lane < NP) {
      const int cc = (lane < g) ? lane : lane + 2;     // companion qubit, skips g,g+1
      const int a0 = (g  < cc) ? g  : cc,  a1 = (g  < cc) ? cc : g;
      const int g1 = g + 1;
      const int b0 = (g1 < cc) ? g1 : cc,  b1 = (g1 < cc) ? cc : g1;
      const int i = pair_idx(a0, a1);                  // state containing g
      const int j = pair_idx(b0, b1);                  // state containing g+1
      const float c = csc[g], s = css[g];
      const float vi = v[i], vj = v[j];
      v[i] = c * vi - s * vj;
      v[j] = s * vi + c * vj;
    }
    // pairs within a gate are disjoint; DS ops are in-order per wave.
    // wave_barrier only pins compiler scheduling across gates.
    __builtin_amdgcn_wave_barrier();
  }

  float4* dst = (float4*)(out + row * (size_t)D);
  for (int e = lane; e < D / 4; e += 64) dst[e] = v4[e];
}

// Phase B: out = V @ S, in place. Workgroup stages a [780 x KT] column tile
// in LDS, applies the same rotations along the row axis, writes back.
__global__ __launch_bounds__(512) void rbs_row_kernel(
    float* __restrict__ data, const float* __restrict__ ang) {
  __shared__ float csc[NG], css[NG];
  __shared__ float vb[D * PAD];           // 53,040 B
  const int tid = threadIdx.x;
  if (tid < NG) {
    float s, c;
    sincosf(ang[tid], &s, &c);
    csc[tid] = c; css[tid] = s;
  }
  const int b  = blockIdx.y;
  const int k0 = blockIdx.x * KT;
  const int ncols = (k0 + KT <= D) ? KT : (D - k0);    // 16, last tile 12
  float* base = data + (size_t)b * D * D + k0;

  const int fc = (tid & 3) * 4;           // float4 column offset within tile
  const int r0 = tid >> 2;                // 128 rows per sweep
  if (fc < ncols) {
    for (int r = r0; r < D; r += 128) {
      float4 x = *(const float4*)(base + (size_t)r * D + fc);
      float* p = &vb[r * PAD + fc];
      p[0] = x.x; p[1] = x.y; p[2] = x.z; p[3] = x.w;
    }
  }
  __syncthreads();

  const int pbase = tid >> 4;             // 0..31 (pair id)
  const int col   = tid & 15;
  for (int g = 0; g < NG; ++g) {
    const float c = csc[g], s = css[g];
    #pragma unroll
    for (int chunk = 0; chunk < 2; ++chunk) {
      const int pp = pbase + chunk * 32;
      if (pp < NP && col < ncols) {
        const int cc = (pp < g) ? pp : pp + 2;
        const int a0 = (g  < cc) ? g  : cc,  a1 = (g  < cc) ? cc : g;
        const int g1 = g + 1;
        const int b0 = (g1 < cc) ? g1 : cc,  b1 = (g1 < cc) ? cc : g1;
        const int i = pair_idx(a0, a1) * PAD + col;
        const int j = pair_idx(b0, b1) * PAD + col;
        const float vi = vb[i], vj = vb[j];
        vb[i] = c * vi - s * vj;
        vb[j] = s * vi + c * vj;
      }
    }
    __syncthreads();                      // cross-wave hazard between gates
  }

  if (fc < ncols) {
    for (int r = r0; r < D; r += 128) {
      float* p = &vb[r * PAD + fc];
      *(float4*)(base + (size_t)r * D + fc) = make_float4(p[0], p[1], p[2], p[3]);
    }
  }
}

extern "C" void kernel_launch(void* const* d_in, const int* in_sizes, int n_in,
                              void* d_out, int out_size, void* d_ws, size_t ws_size,
                              hipStream_t stream) {
  const float* rho = (const float*)d_in[0];   // [B, 780, 780] f32
  const float* ang = (const float*)d_in[1];   // [39] f32
  float* out = (float*)d_out;                 // [B, 780, 780] f32
  const int batch = in_sizes[0] / (D * D);    // 64

  // Phase A: column rotations rho -> out. One wave per row, 4 waves/block.
  const int nrows = batch * D;                // 49,920 (divisible by 4)
  rbs_col_kernel<<<dim3(nrows / 4), 256, 0, stream>>>(rho, ang, out);

  // Phase B: row rotations in place on out. Tiles disjoint in columns.
  rbs_row_kernel<<<dim3((D + KT - 1) / KT, batch), 512, 0, stream>>>(out, ang);
}

// Round 2
// 517.668 us; speedup vs baseline: 1.0046x; 1.0046x over previous
//
#include <hip/hip_runtime.h>

#define D   780   // binom(40,2)
#define NG  39    // gates
#define NP  38    // rotation pairs per gate
#define KT  16    // columns per block in row-phase (= waves per block)

// index of basis state {p,q}, p<q, in lexicographic combinations(range(40),2)
__device__ __forceinline__ int pair_idx(int p, int q) {
  return (p * (79 - p)) / 2 + (q - p - 1);
}

// Phase A: S = rho @ V^T. Each wave owns one contiguous 780-float row.
// Column rotation within a row: v[i] <- c*v[i] - s*v[j]; v[j] <- s*v[i] + c*v[j]
// where i = idx({g,c}), j = idx({g+1,c}).
__global__ __launch_bounds__(256) void rbs_col_kernel(
    const float* __restrict__ rho, const float* __restrict__ ang,
    float* __restrict__ out) {
  __shared__ float csc[NG], css[NG];
  __shared__ float vbuf[4][D];            // one 780-float row per wave
  const int tid = threadIdx.x;
  if (tid < NG) {
    float s, c;
    sincosf(ang[tid], &s, &c);
    csc[tid] = c; css[tid] = s;
  }
  __syncthreads();

  const int wave = tid >> 6, lane = tid & 63;
  const size_t row = (size_t)blockIdx.x * 4 + wave;   // global row id (b*780 + r)
  const float4* src = (const float4*)(rho + row * (size_t)D);
  float* v = vbuf[wave];
  float4* v4 = (float4*)v;                            // 3120B row stride: 16B aligned

  for (int e = lane; e < D / 4; e += 64) v4[e] = src[e];   // 195 float4 per row
  __builtin_amdgcn_wave_barrier();

  for (int g = 0; g < NG; ++g) {
    if (lane < NP) {
      const int cc = (lane < g) ? lane : lane + 2;     // companion qubit, skips g,g+1
      const int a0 = (g  < cc) ? g  : cc,  a1 = (g  < cc) ? cc : g;
      const int g1 = g + 1;
      const int b0 = (g1 < cc) ? g1 : cc,  b1 = (g1 < cc) ? cc : g1;
      const int i = pair_idx(a0, a1);                  // state containing g
      const int j = pair_idx(b0, b1);                  // state containing g+1
      const float c = csc[g], s = css[g];
      const float vi = v[i], vj = v[j];
      v[i] = c * vi - s * vj;
      v[j] = s * vi + c * vj;
    }
    // pairs within a gate are disjoint; DS ops are in-order per wave.
    __builtin_amdgcn_wave_barrier();
  }

  float4* dst = (float4*)(out + row * (size_t)D);
  for (int e = lane; e < D / 4; e += 64) dst[e] = v4[e];
}

// Phase B: out = V @ S, in place. Block stages a [780 x 16] column tile in LDS
// (column-major), then each of 16 waves runs the FULL 39-gate chain on its own
// column with no __syncthreads (per-wave in-order DS ops), then writeback.
__global__ __launch_bounds__(1024) void rbs_row_kernel(
    float* __restrict__ data, const float* __restrict__ ang) {
  __shared__ float csc[NG], css[NG];
  __shared__ float vb[KT][D];             // 49,920 B -> 2 blocks/CU, 32 waves/CU
  const int tid = threadIdx.x;
  if (tid < NG) {
    float s, c;
    sincosf(ang[tid], &s, &c);
    csc[tid] = c; css[tid] = s;
  }
  const int b  = blockIdx.y;
  const int k0 = blockIdx.x * KT;
  const int ncols = (D - k0 < KT) ? (D - k0) : KT;     // 16, last tile 12
  float* base = data + (size_t)b * D * D + k0;

  // cooperative stage-in: thread t loads float4 of row r=t>>2, cols fc..fc+3,
  // scatters into column-major LDS (2-way bank pattern = free).
  const int fc = (tid & 3) * 4;
  const int r0 = tid >> 2;                // 0..255
  if (fc < ncols) {
    for (int r = r0; r < D; r += 256) {
      float4 x = *(const float4*)(base + (size_t)r * D + fc);
      vb[fc + 0][r] = x.x; vb[fc + 1][r] = x.y;
      vb[fc + 2][r] = x.z; vb[fc + 3][r] = x.w;
    }
  }
  __syncthreads();

  const int w = tid >> 6, lane = tid & 63;
  if (w < ncols) {
    float* v = vb[w];
    for (int g = 0; g < NG; ++g) {
      if (lane < NP) {
        const int cc = (lane < g) ? lane : lane + 2;
        const int a0 = (g  < cc) ? g  : cc,  a1 = (g  < cc) ? cc : g;
        const int g1 = g + 1;
        const int b0 = (g1 < cc) ? g1 : cc,  b1 = (g1 < cc) ? cc : g1;
        const int i = pair_idx(a0, a1);
        const int j = pair_idx(b0, b1);
        const float c = csc[g], s = css[g];
        const float vi = v[i], vj = v[j];
        v[i] = c * vi - s * vj;
        v[j] = s * vi + c * vj;
      }
      __builtin_amdgcn_wave_barrier();
    }
  }
  __syncthreads();

  if (fc < ncols) {
    for (int r = r0; r < D; r += 256) {
      float4 x = make_float4(vb[fc + 0][r], vb[fc + 1][r],
                             vb[fc + 2][r], vb[fc + 3][r]);
      *(float4*)(base + (size_t)r * D + fc) = x;
    }
  }
}

extern "C" void kernel_launch(void* const* d_in, const int* in_sizes, int n_in,
                              void* d_out, int out_size, void* d_ws, size_t ws_size,
                              hipStream_t stream) {
  const float* rho = (const float*)d_in[0];   // [B, 780, 780] f32
  const float* ang = (const float*)d_in[1];   // [39] f32
  float* out = (float*)d_out;                 // [B, 780, 780] f32
  const int batch = in_sizes[0] / (D * D);    // 64

  // Phase A: column rotations rho -> out. One wave per row, 4 waves/block.
  const int nrows = batch * D;                // 49,920 (divisible by 4)
  rbs_col_kernel<<<dim3(nrows / 4), 256, 0, stream>>>(rho, ang, out);

  // Phase B: row rotations in place on out. Tiles disjoint in columns.
  rbs_row_kernel<<<dim3((D + KT - 1) / KT, batch), 1024, 0, stream>>>(out, ang);
}

// Round 3
// 508.458 us; speedup vs baseline: 1.0228x; 1.0181x over previous
//
#include <hip/hip_runtime.h>

#define D   780   // binom(40,2)
#define NG  39    // gates
#define NP  38    // rotation pairs per gate
#define KT  16    // columns per block in row-phase (= waves per block)

// index of basis state {p,q}, p<q, in lexicographic combinations(range(40),2)
__device__ __forceinline__ int pair_idx(int p, int q) {
  return (p * (79 - p)) / 2 + (q - p - 1);
}

// Build constant-per-launch tables in LDS:
//   tbl[g*NP+p] = (byte_off_i << 16) | byte_off_j   (i contains qubit g, j contains g+1)
//   cs[g] = {cos(theta_g), sin(theta_g)}
__device__ __forceinline__ void build_tables(uint* tbl, float2* cs,
                                             const float* __restrict__ ang,
                                             int tid, int nthr) {
  for (int t = tid; t < NG * NP; t += nthr) {
    const int g = t / NP, p = t - g * NP;
    const int cc = (p < g) ? p : p + 2;      // companion qubit, skips g,g+1
    const int g1 = g + 1;
    const int a0 = (g  < cc) ? g  : cc,  a1 = (g  < cc) ? cc : g;
    const int b0 = (g1 < cc) ? g1 : cc,  b1 = (g1 < cc) ? cc : g1;
    const uint i4 = (uint)pair_idx(a0, a1) * 4u;
    const uint j4 = (uint)pair_idx(b0, b1) * 4u;
    tbl[t] = (i4 << 16) | j4;
  }
  if (tid < NG) {
    float s, c;
    sincosf(ang[tid], &s, &c);
    cs[tid] = make_float2(c, s);
  }
}

// Apply the full 39-gate chain to one wave-owned 780-float vector in LDS.
// Per-wave DS ops are in-order; wave_barrier only pins compiler scheduling.
__device__ __forceinline__ void run_chain(float* __restrict__ v,
                                          const uint* __restrict__ tbl,
                                          const float2* __restrict__ cs,
                                          int lane) {
  char* vb = (char*)v;
  if (lane < NP) {
    #pragma unroll
    for (int g = 0; g < NG; ++g) {
      const uint pk = tbl[g * NP + lane];    // imm-offset ds_read_b32, conflict-free
      const float2 sc = cs[g];               // broadcast ds_read_b64
      float* pi = (float*)(vb + (pk >> 16));
      float* pj = (float*)(vb + (pk & 0xffffu));
      const float vi = *pi, vj = *pj;
      *pi = sc.x * vi - sc.y * vj;
      *pj = sc.y * vi + sc.x * vj;
      __builtin_amdgcn_wave_barrier();
    }
  }
}

// Phase A: out_row = V @ rho_row for every row (contiguous 780 floats).
// 8 waves/block, one row per wave.
__global__ __launch_bounds__(512) void rbs_col_kernel(
    const float* __restrict__ rho, const float* __restrict__ ang,
    float* __restrict__ out) {
  __shared__ uint   tbl[NG * NP];
  __shared__ float2 cs[NG];
  __shared__ float  vbuf[8][D];
  build_tables(tbl, cs, ang, threadIdx.x, 512);
  __syncthreads();

  const int wave = threadIdx.x >> 6, lane = threadIdx.x & 63;
  const size_t row = (size_t)blockIdx.x * 8 + wave;   // b*780 + r
  const float4* src = (const float4*)(rho + row * (size_t)D);
  float* v = vbuf[wave];
  float4* v4 = (float4*)v;

  for (int e = lane; e < D / 4; e += 64) v4[e] = src[e];
  __builtin_amdgcn_wave_barrier();

  run_chain(v, tbl, cs, lane);

  float4* dst = (float4*)(out + row * (size_t)D);
  for (int e = lane; e < D / 4; e += 64) dst[e] = v4[e];
}

// Phase B: out = V @ S in place. Block stages a [780 x 16] column tile
// column-major in LDS; each of 16 waves runs the chain on its own column.
__global__ __launch_bounds__(1024) void rbs_row_kernel(
    float* __restrict__ data, const float* __restrict__ ang) {
  __shared__ uint   tbl[NG * NP];
  __shared__ float2 cs[NG];
  __shared__ float  vb[KT][D];            // 49,920 B -> 2 blocks/CU, 32 waves/CU
  build_tables(tbl, cs, ang, threadIdx.x, 1024);

  const int b  = blockIdx.y;
  const int k0 = blockIdx.x * KT;
  const int ncols = (D - k0 < KT) ? (D - k0) : KT;     // 16, last tile 12
  float* base = data + (size_t)b * D * D + k0;

  const int fc = (threadIdx.x & 3) * 4;   // float4 column offset within tile
  const int r0 = threadIdx.x >> 2;        // 0..255
  if (fc < ncols) {
    for (int r = r0; r < D; r += 256) {
      float4 x = *(const float4*)(base + (size_t)r * D + fc);
      vb[fc + 0][r] = x.x; vb[fc + 1][r] = x.y;
      vb[fc + 2][r] = x.z; vb[fc + 3][r] = x.w;
    }
  }
  __syncthreads();

  const int w = threadIdx.x >> 6, lane = threadIdx.x & 63;
  if (w < ncols) run_chain(vb[w], tbl, cs, lane);
  __syncthreads();

  if (fc < ncols) {
    for (int r = r0; r < D; r += 256) {
      float4 x = make_float4(vb[fc + 0][r], vb[fc + 1][r],
                             vb[fc + 2][r], vb[fc + 3][r]);
      *(float4*)(base + (size_t)r * D + fc) = x;
    }
  }
}

extern "C" void kernel_launch(void* const* d_in, const int* in_sizes, int n_in,
                              void* d_out, int out_size, void* d_ws, size_t ws_size,
                              hipStream_t stream) {
  const float* rho = (const float*)d_in[0];   // [B, 780, 780] f32
  const float* ang = (const float*)d_in[1];   // [39] f32
  float* out = (float*)d_out;                 // [B, 780, 780] f32
  const int batch = in_sizes[0] / (D * D);    // 64

  // Phase A: row vectors, 8 rows per block.
  const int nrows = batch * D;                // 49,920 (divisible by 8)
  rbs_col_kernel<<<dim3(nrows / 8), 512, 0, stream>>>(rho, ang, out);

  // Phase B: column vectors, in place on out.
  rbs_row_kernel<<<dim3((D + KT - 1) / KT, batch), 1024, 0, stream>>>(out, ang);
}